// Round 11
// baseline (190.008 us; speedup 1.0000x reference)
//
#include <hip/hip_runtime.h>

// LeNet-5 forward, fully fused, TWO WAVES PER IMAGE (128-thread blocks).
// ALL three convs on bf16 MFMA (16x16x32); only epilogues + fc on VALU.
//
// Round-11: round-10 showed zero pipe overlap (dur == sum of per-pipe times;
// grid-capped at 16 single-wave blocks/CU). Splitting each image across 2
// waves halves the per-wave critical path and raises resident waves/CU from
// ~14 to ~24, letting MFMA/LDS/VALU overlap toward the busiest-pipe bound.
// Work split: conv1 nt-groups 1/wave (exact); conv2 M-tiles 4+3 (+1 dummy,
// epilogue-masked); conv3 2+1 (+1 dummy). Real __syncthreads() between
// producer/consumer phases. fc reduced across waves via LDS partials.
//
// Layouts (unchanged from round 7):
//   conv1 as GEMM (row-only im2col), banded weights K=288, N=192.
//   h1: bf16 19x248 ([x*12+c], pads zeroed)  -- stride 248 = conflict-free
//   h2: bf16 10x248 ([x*20+c], pads zeroed)
//   all K-padding baked into pre-packed weights (zeros).

typedef short s16x4 __attribute__((ext_vector_type(4)));
typedef short s16x8 __attribute__((ext_vector_type(8)));
typedef float f32x4 __attribute__((ext_vector_type(4)));

#define ROW1 248
#define ROW2 248
#define XOFF 4712           // xbf elem offset (= 19*248)
#define SM_BYTES 11024

static __device__ __forceinline__ unsigned short f2bf(float f) {
    union { float f; unsigned int u; } v; v.f = f;
    unsigned int u = v.u;
    unsigned int r = (u + 0x7fffu + ((u >> 16) & 1u)) >> 16;   // RNE
    return (unsigned short)r;
}

static __device__ __forceinline__ s16x8 cat8(s16x4 lo, s16x4 hi) {
    return __builtin_shufflevector(lo, hi, 0, 1, 2, 3, 4, 5, 6, 7);
}

// ---- weight prep ----------------------------------------------------------
// wbuf ushort: [0,40960) conv2 B-frags, [40960,61440) conv3 B-frags,
//              [61440,116736) conv1 banded B-frags (wband).
// All use the 16x16x32 B-frag convention: n = nt*16 + (lane&15),
// k = kc*32 + ((lane>>4)&3)*8 + t.
__global__ __launch_bounds__(256) void wprep_k(const float* __restrict__ w1,
                                               const float* __restrict__ w2,
                                               const float* __restrict__ w3,
                                               unsigned short* __restrict__ wbuf) {
    int e = blockIdx.x * 256 + threadIdx.x;
    if (e < 40960) {                       // conv2: j=k/12, c=k%12
        int t = e & 7, lane = (e >> 3) & 63, nt = (e >> 9) & 1;
        int ck = (e >> 10) & 3, i = e >> 12;
        int k = ck * 32 + ((lane >> 4) & 3) * 8 + t;
        int o = nt * 16 + (lane & 15);
        int j = k / 12, c = k % 12;
        float val = (j < 10 && c < 10 && o < 20) ? w2[o * 1000 + c * 100 + i * 10 + j] : 0.f;
        wbuf[e] = f2bf(val);
    } else if (e < 61440) {                // conv3: j=k/20, c=k%20
        int e2 = e - 40960;
        int t = e2 & 7, lane = (e2 >> 3) & 63, nt = (e2 >> 9) & 1;
        int ck = (e2 >> 10) & 3, i = e2 >> 12;
        int k = ck * 32 + ((lane >> 4) & 3) * 8 + t;
        int o = nt * 16 + (lane & 15);
        int j = k / 20, c = k % 20;
        float val = (j < 5 && o < 20) ? w3[o * 500 + c * 25 + i * 5 + j] : 0.f;
        wbuf[e] = f2bf(val);
    } else {                               // conv1 band: [nt(12)][kc(9)][lane][t]
        int e2 = e - 61440;                // < 55296
        int t = e2 & 7, lane = (e2 >> 3) & 63;
        int kc = (e2 >> 9) % 9, nt = (e2 >> 9) / 9;
        int n = nt * 16 + (lane & 15);
        int k = kc * 32 + ((lane >> 4) & 3) * 8 + t;
        float val = 0.f;
        if (n < 190 && k < 280) {
            int ox = n / 10, o = n - ox * 10;
            int i = k / 28, xc = k - i * 28;
            int j = xc - ox;
            if (j >= 0 && j < 10) val = w1[o * 100 + i * 10 + j];
        }
        wbuf[61440 + e2] = f2bf(val);
    }
}

// --------------------------- the fused kernel ------------------------------
__global__ __launch_bounds__(128, 6) void fused_k(const float* __restrict__ x,
                                                  const float* __restrict__ b1,
                                                  const unsigned short* __restrict__ wbuf2,
                                                  const unsigned short* __restrict__ wbuf3,
                                                  const unsigned short* __restrict__ wband,
                                                  const float* __restrict__ b2,
                                                  const float* __restrict__ b3,
                                                  const float* __restrict__ wf,
                                                  const float* __restrict__ bf,
                                                  float* __restrict__ out) {
    __shared__ __align__(16) unsigned char smem[SM_BYTES];
    unsigned short* sm16 = (unsigned short*)smem;
    unsigned short* h1  = sm16;                 // [0, 4712) elems
    unsigned short* xbf = sm16 + XOFF;          // [4712, 5512) elems
    unsigned short* h2s = sm16;                 // later: [0, 2480) elems
    float*          h3s = (float*)smem;         // later: [0, 720) floats
    float*          fcp = (float*)(smem + 2880);// fc partials (20 floats)

    const int tid = threadIdx.x;
    const int wave = tid >> 6, lane = tid & 63;
    const int b = blockIdx.x;
    const int quad = lane >> 4, lm = lane & 15;

    // ---- phase 1: stage x as bf16; zero xbf tail, h1 row-pads & c-pads ----
    {
        const float4* src = (const float4*)(x + (size_t)b * 784);
        for (int k = tid; k < 196; k += 128) {
            float4 v = src[k];
            s16x4 p = { (short)f2bf(v.x), (short)f2bf(v.y),
                        (short)f2bf(v.z), (short)f2bf(v.w) };
            *(s16x4*)(xbf + k * 4) = p;
        }
        if (tid < 16) xbf[784 + tid] = 0;
        for (int e = tid; e < 95; e += 128) {          // row pads [228,248) x 19
            int row = e / 5, seg = e - row * 5;
            *(s16x4*)(h1 + row * ROW1 + 228 + seg * 4) = (s16x4){0, 0, 0, 0};
        }
        for (int e = tid; e < 361; e += 128) {         // c-pads (oy,ox,[10,12))
            int oy = e / 19, ox = e - oy * 19;
            *(unsigned int*)(h1 + oy * ROW1 + ox * 12 + 10) = 0u;
        }
    }
    __syncthreads();

    // ---- phase 2: conv1 MFMA  M=32(19), N=192(190), K=288(280) ----
    // nt-group g == wave (6 nt each): exact 2-way split.
    {
        int m1 = lm + 16; if (m1 > 18) m1 = 18;        // clamp pad rows
        const unsigned short* ab0 = xbf + lm * 28 + quad * 8;
        const unsigned short* ab1 = xbf + m1 * 28 + quad * 8;
        const unsigned short* wb = wband + lane * 8;
        f32x4 acc1[6][2] = {};
#pragma unroll
        for (int kc = 0; kc < 9; ++kc) {
            s16x8 a0 = cat8(*(const s16x4*)(ab0 + kc * 32),
                            *(const s16x4*)(ab0 + kc * 32 + 4));
            s16x8 a1 = cat8(*(const s16x4*)(ab1 + kc * 32),
                            *(const s16x4*)(ab1 + kc * 32 + 4));
#pragma unroll
            for (int q = 0; q < 6; ++q) {
                int nt = wave * 6 + q;
                s16x8 bw = *(const s16x8*)(wb + (nt * 9 + kc) * 512);
                acc1[q][0] = __builtin_amdgcn_mfma_f32_16x16x32_bf16(a0, bw, acc1[q][0], 0, 0, 0);
                acc1[q][1] = __builtin_amdgcn_mfma_f32_16x16x32_bf16(a1, bw, acc1[q][1], 0, 0, 0);
            }
        }
#pragma unroll
        for (int q = 0; q < 6; ++q) {
            int n = (wave * 6 + q) * 16 + lm;
            if (n < 190) {
                int ox = n / 10, o = n - ox * 10;
                float bias = b1[o];
#pragma unroll
                for (int mt = 0; mt < 2; ++mt) {
#pragma unroll
                    for (int r = 0; r < 4; ++r) {
                        int oy = mt * 16 + quad * 4 + r;
                        if (oy < 19)
                            h1[oy * ROW1 + ox * 12 + o] =
                                f2bf(fmaxf(acc1[q][mt][r] + bias, 0.f));
                    }
                }
            }
        }
    }
    __syncthreads();

    // ---- phase 3: conv2 MFMA  M=112(100), N=32(20), K=1280(1000) ----
    // Tiles: wave0 -> {0,1,2,3}, wave1 -> {4,5,6,dummy}. 40 unrolled steps,
    // distance-1 weight prefetch in named SSA vars.
    int abase[4];
#pragma unroll
    for (int mt = 0; mt < 4; ++mt) {
        int m = (wave * 4 + mt) * 16 + lm;
        if (m > 99) m = 99;                  // dummy/pad rows: duplicate
        int y = m / 10, xx = m - 10 * y;
        abase[mt] = y * ROW1 + xx * 12 + quad * 8;
    }
    f32x4 acc[4][2] = {};
    {
        const unsigned short* wptr = wbuf2 + lane * 8;
        s16x8 wc0 = *(const s16x8*)(wptr);
        s16x8 wc1 = *(const s16x8*)(wptr + 512);
#pragma unroll
        for (int it = 0; it < 40; ++it) {
            s16x8 wn0 = *(const s16x8*)(wptr + (it + 1) * 1024);   // tail -> conv3 region
            s16x8 wn1 = *(const s16x8*)(wptr + (it + 1) * 1024 + 512);
            const unsigned short* sbi = h1 + (it >> 2) * ROW1 + (it & 3) * 32;
            s16x8 af[4];
#pragma unroll
            for (int mt = 0; mt < 4; ++mt) {
                const unsigned short* p = sbi + abase[mt];
                af[mt] = cat8(*(const s16x4*)(p), *(const s16x4*)(p + 4));
            }
#pragma unroll
            for (int mt = 0; mt < 4; ++mt) {
                acc[mt][0] = __builtin_amdgcn_mfma_f32_16x16x32_bf16(af[mt], wc0, acc[mt][0], 0, 0, 0);
                acc[mt][1] = __builtin_amdgcn_mfma_f32_16x16x32_bf16(af[mt], wc1, acc[mt][1], 0, 0, 0);
            }
            wc0 = wn0; wc1 = wn1;
        }
    }
    __syncthreads();   // h1 fully consumed by both waves; region becomes h2s

    // ---- phase 4: zero h2 row-pads + scatter conv2 -> h2s ([x*20+c]) ----
    for (int e = tid; e < 120; e += 128) {             // pads [200,248) x 10
        int row = e / 12, seg = e - row * 12;
        *(s16x4*)(h2s + row * ROW2 + 200 + seg * 4) = (s16x4){0, 0, 0, 0};
    }
#pragma unroll
    for (int mt = 0; mt < 4; ++mt) {
        int mtg = wave * 4 + mt;
        if (mtg < 7) {                                  // skip wave1 dummy
#pragma unroll
            for (int nt = 0; nt < 2; ++nt) {
                int o = nt * 16 + lm;
                if (o < 20) {
                    float bias = b2[o];
#pragma unroll
                    for (int r = 0; r < 4; ++r) {
                        int pos = mtg * 16 + quad * 4 + r;
                        if (pos < 100) {
                            int y2 = pos / 10, x2 = pos - 10 * y2;
                            h2s[y2 * ROW2 + x2 * 20 + o] =
                                f2bf(fmaxf(acc[mt][nt][r] + bias, 0.f));
                        }
                    }
                }
            }
        }
    }
    __syncthreads();

    // ---- phase 5: conv3 MFMA  M=48(36), N=32(20), K=640(500) ----
    // Tiles: wave0 -> {0,1}, wave1 -> {2,dummy}. 20 unrolled steps.
    int abase3[2];
#pragma unroll
    for (int mt = 0; mt < 2; ++mt) {
        int m = (wave * 2 + mt) * 16 + lm;
        if (m > 35) m = 35;
        int oy = m / 6, ox = m - 6 * oy;
        abase3[mt] = oy * ROW2 + ox * 20 + quad * 8;
    }
    f32x4 acc3[2][2] = {};
    {
        const unsigned short* wptr = wbuf3 + lane * 8;
        s16x8 wc0 = *(const s16x8*)(wptr);
        s16x8 wc1 = *(const s16x8*)(wptr + 512);
#pragma unroll
        for (int it = 0; it < 20; ++it) {
            s16x8 wn0 = *(const s16x8*)(wptr + (it + 1) * 1024);   // tail -> wband
            s16x8 wn1 = *(const s16x8*)(wptr + (it + 1) * 1024 + 512);
            const unsigned short* sbi = h2s + (it >> 2) * ROW2 + (it & 3) * 32;
            s16x8 af[2];
#pragma unroll
            for (int mt = 0; mt < 2; ++mt) {
                const unsigned short* p = sbi + abase3[mt];
                af[mt] = cat8(*(const s16x4*)(p), *(const s16x4*)(p + 4));
            }
#pragma unroll
            for (int mt = 0; mt < 2; ++mt) {
                acc3[mt][0] = __builtin_amdgcn_mfma_f32_16x16x32_bf16(af[mt], wc0, acc3[mt][0], 0, 0, 0);
                acc3[mt][1] = __builtin_amdgcn_mfma_f32_16x16x32_bf16(af[mt], wc1, acc3[mt][1], 0, 0, 0);
            }
            wc0 = wn0; wc1 = wn1;
        }
    }
    __syncthreads();   // h2s consumed by both waves; region becomes h3s

    // ---- phase 6: conv3 epilogue -> linear h3s[o*36+pos] (fp32, relu) ----
#pragma unroll
    for (int mt = 0; mt < 2; ++mt) {
        int mtg = wave * 2 + mt;
        if (mtg < 3) {                                  // skip wave1 dummy
#pragma unroll
            for (int nt = 0; nt < 2; ++nt) {
                int o = nt * 16 + lm;
                if (o < 20) {
                    float b3v = b3[o];
#pragma unroll
                    for (int r = 0; r < 4; ++r) {
                        int pos = mtg * 16 + quad * 4 + r;
                        if (pos < 36)
                            h3s[o * 36 + pos] = fmaxf(acc3[mt][nt][r] + b3v, 0.f);
                    }
                }
            }
        }
    }
    __syncthreads();

    // ---- phase 7: fc — coalesced global wf; 128 threads; 2-wave reduce ----
    float part[10];
#pragma unroll
    for (int n = 0; n < 10; ++n) part[n] = 0.f;
#pragma unroll 1
    for (int s = 0; s < 6; ++s) {
        int k = s * 128 + tid;
        if (k < 720) {
            float v = h3s[k];
#pragma unroll
            for (int n = 0; n < 10; ++n)
                part[n] = fmaf(v, wf[n * 720 + k], part[n]);
        }
    }
#pragma unroll
    for (int n = 0; n < 10; ++n) {
#pragma unroll
        for (int off = 32; off >= 1; off >>= 1)
            part[n] += __shfl_xor(part[n], off, 64);
    }
    if (lane == 0) {
#pragma unroll
        for (int n = 0; n < 10; ++n) fcp[wave * 10 + n] = part[n];
    }
    __syncthreads();
    if (tid < 10)
        out[(size_t)b * 10 + tid] = fcp[tid] + fcp[10 + tid] + bf[tid];
}

extern "C" void kernel_launch(void* const* d_in, const int* in_sizes, int n_in,
                              void* d_out, int out_size, void* d_ws, size_t ws_size,
                              hipStream_t stream) {
    (void)n_in; (void)out_size; (void)ws_size;
    const float* x  = (const float*)d_in[0];
    const float* w1 = (const float*)d_in[1];
    const float* b1 = (const float*)d_in[2];
    const float* w2 = (const float*)d_in[3];
    const float* b2 = (const float*)d_in[4];
    const float* w3 = (const float*)d_in[5];
    const float* b3 = (const float*)d_in[6];
    const float* wf = (const float*)d_in[7];
    const float* bf = (const float*)d_in[8];
    float* out = (float*)d_out;

    const int B = in_sizes[0] / 784;                   // 4096

    unsigned short* wbuf = (unsigned short*)d_ws;      // 116736 bf16 = 228 KB

    wprep_k<<<456, 256, 0, stream>>>(w1, w2, w3, wbuf);
    fused_k<<<B, 128, 0, stream>>>(x, b1, wbuf, wbuf + 40960, wbuf + 61440,
                                   b2, b3, wf, bf, out);
}

// Round 12
// 154.448 us; speedup vs baseline: 1.2302x; 1.2302x over previous
//
#include <hip/hip_runtime.h>

// LeNet-5 forward, fully fused, TWO WAVES PER IMAGE (128-thread blocks).
// ALL three convs on bf16 MFMA (16x16x32); only epilogues + fc on VALU.
//
// Round-12: round-11's ONLY defect was __launch_bounds__(128,6): the 2nd arg
// caps the UNIFIED VGPR+AGPR budget at 512/6~=85/wave; the per-wave working
// set (~105: arch regs + MFMA accs in AGPRs + prefetch) spilled to scratch
// (WRITE_SIZE 116 MB). This round: (128,4) -> 128-reg cap, zero spill.
// Everything else identical to round 11. Occupancy ~16 waves/CU (VGPR-bound),
// ~2x round-10's residency; 2-wave split halves per-wave critical path.
//
// Layouts (unchanged from round 7):
//   conv1 as GEMM (row-only im2col), banded weights K=288, N=192.
//   h1: bf16 19x248 ([x*12+c], pads zeroed)  -- stride 248 = conflict-free
//   h2: bf16 10x248 ([x*20+c], pads zeroed)
//   all K-padding baked into pre-packed weights (zeros).

typedef short s16x4 __attribute__((ext_vector_type(4)));
typedef short s16x8 __attribute__((ext_vector_type(8)));
typedef float f32x4 __attribute__((ext_vector_type(4)));

#define ROW1 248
#define ROW2 248
#define XOFF 4712           // xbf elem offset (= 19*248)
#define SM_BYTES 11024

static __device__ __forceinline__ unsigned short f2bf(float f) {
    union { float f; unsigned int u; } v; v.f = f;
    unsigned int u = v.u;
    unsigned int r = (u + 0x7fffu + ((u >> 16) & 1u)) >> 16;   // RNE
    return (unsigned short)r;
}

static __device__ __forceinline__ s16x8 cat8(s16x4 lo, s16x4 hi) {
    return __builtin_shufflevector(lo, hi, 0, 1, 2, 3, 4, 5, 6, 7);
}

// ---- weight prep ----------------------------------------------------------
// wbuf ushort: [0,40960) conv2 B-frags, [40960,61440) conv3 B-frags,
//              [61440,116736) conv1 banded B-frags (wband).
// All use the 16x16x32 B-frag convention: n = nt*16 + (lane&15),
// k = kc*32 + ((lane>>4)&3)*8 + t.
__global__ __launch_bounds__(256) void wprep_k(const float* __restrict__ w1,
                                               const float* __restrict__ w2,
                                               const float* __restrict__ w3,
                                               unsigned short* __restrict__ wbuf) {
    int e = blockIdx.x * 256 + threadIdx.x;
    if (e < 40960) {                       // conv2: j=k/12, c=k%12
        int t = e & 7, lane = (e >> 3) & 63, nt = (e >> 9) & 1;
        int ck = (e >> 10) & 3, i = e >> 12;
        int k = ck * 32 + ((lane >> 4) & 3) * 8 + t;
        int o = nt * 16 + (lane & 15);
        int j = k / 12, c = k % 12;
        float val = (j < 10 && c < 10 && o < 20) ? w2[o * 1000 + c * 100 + i * 10 + j] : 0.f;
        wbuf[e] = f2bf(val);
    } else if (e < 61440) {                // conv3: j=k/20, c=k%20
        int e2 = e - 40960;
        int t = e2 & 7, lane = (e2 >> 3) & 63, nt = (e2 >> 9) & 1;
        int ck = (e2 >> 10) & 3, i = e2 >> 12;
        int k = ck * 32 + ((lane >> 4) & 3) * 8 + t;
        int o = nt * 16 + (lane & 15);
        int j = k / 20, c = k % 20;
        float val = (j < 5 && o < 20) ? w3[o * 500 + c * 25 + i * 5 + j] : 0.f;
        wbuf[e] = f2bf(val);
    } else {                               // conv1 band: [nt(12)][kc(9)][lane][t]
        int e2 = e - 61440;                // < 55296
        int t = e2 & 7, lane = (e2 >> 3) & 63;
        int kc = (e2 >> 9) % 9, nt = (e2 >> 9) / 9;
        int n = nt * 16 + (lane & 15);
        int k = kc * 32 + ((lane >> 4) & 3) * 8 + t;
        float val = 0.f;
        if (n < 190 && k < 280) {
            int ox = n / 10, o = n - ox * 10;
            int i = k / 28, xc = k - i * 28;
            int j = xc - ox;
            if (j >= 0 && j < 10) val = w1[o * 100 + i * 10 + j];
        }
        wbuf[61440 + e2] = f2bf(val);
    }
}

// --------------------------- the fused kernel ------------------------------
__global__ __launch_bounds__(128, 4) void fused_k(const float* __restrict__ x,
                                                  const float* __restrict__ b1,
                                                  const unsigned short* __restrict__ wbuf2,
                                                  const unsigned short* __restrict__ wbuf3,
                                                  const unsigned short* __restrict__ wband,
                                                  const float* __restrict__ b2,
                                                  const float* __restrict__ b3,
                                                  const float* __restrict__ wf,
                                                  const float* __restrict__ bf,
                                                  float* __restrict__ out) {
    __shared__ __align__(16) unsigned char smem[SM_BYTES];
    unsigned short* sm16 = (unsigned short*)smem;
    unsigned short* h1  = sm16;                 // [0, 4712) elems
    unsigned short* xbf = sm16 + XOFF;          // [4712, 5512) elems
    unsigned short* h2s = sm16;                 // later: [0, 2480) elems
    float*          h3s = (float*)smem;         // later: [0, 720) floats
    float*          fcp = (float*)(smem + 2880);// fc partials (20 floats)

    const int tid = threadIdx.x;
    const int wave = tid >> 6, lane = tid & 63;
    const int b = blockIdx.x;
    const int quad = lane >> 4, lm = lane & 15;

    // ---- phase 1: stage x as bf16; zero xbf tail, h1 row-pads & c-pads ----
    {
        const float4* src = (const float4*)(x + (size_t)b * 784);
        for (int k = tid; k < 196; k += 128) {
            float4 v = src[k];
            s16x4 p = { (short)f2bf(v.x), (short)f2bf(v.y),
                        (short)f2bf(v.z), (short)f2bf(v.w) };
            *(s16x4*)(xbf + k * 4) = p;
        }
        if (tid < 16) xbf[784 + tid] = 0;
        for (int e = tid; e < 95; e += 128) {          // row pads [228,248) x 19
            int row = e / 5, seg = e - row * 5;
            *(s16x4*)(h1 + row * ROW1 + 228 + seg * 4) = (s16x4){0, 0, 0, 0};
        }
        for (int e = tid; e < 361; e += 128) {         // c-pads (oy,ox,[10,12))
            int oy = e / 19, ox = e - oy * 19;
            *(unsigned int*)(h1 + oy * ROW1 + ox * 12 + 10) = 0u;
        }
    }
    __syncthreads();

    // ---- phase 2: conv1 MFMA  M=32(19), N=192(190), K=288(280) ----
    // nt-group g == wave (6 nt each): exact 2-way split.
    {
        int m1 = lm + 16; if (m1 > 18) m1 = 18;        // clamp pad rows
        const unsigned short* ab0 = xbf + lm * 28 + quad * 8;
        const unsigned short* ab1 = xbf + m1 * 28 + quad * 8;
        const unsigned short* wb = wband + lane * 8;
        f32x4 acc1[6][2] = {};
#pragma unroll
        for (int kc = 0; kc < 9; ++kc) {
            s16x8 a0 = cat8(*(const s16x4*)(ab0 + kc * 32),
                            *(const s16x4*)(ab0 + kc * 32 + 4));
            s16x8 a1 = cat8(*(const s16x4*)(ab1 + kc * 32),
                            *(const s16x4*)(ab1 + kc * 32 + 4));
#pragma unroll
            for (int q = 0; q < 6; ++q) {
                int nt = wave * 6 + q;
                s16x8 bw = *(const s16x8*)(wb + (nt * 9 + kc) * 512);
                acc1[q][0] = __builtin_amdgcn_mfma_f32_16x16x32_bf16(a0, bw, acc1[q][0], 0, 0, 0);
                acc1[q][1] = __builtin_amdgcn_mfma_f32_16x16x32_bf16(a1, bw, acc1[q][1], 0, 0, 0);
            }
        }
#pragma unroll
        for (int q = 0; q < 6; ++q) {
            int n = (wave * 6 + q) * 16 + lm;
            if (n < 190) {
                int ox = n / 10, o = n - ox * 10;
                float bias = b1[o];
#pragma unroll
                for (int mt = 0; mt < 2; ++mt) {
#pragma unroll
                    for (int r = 0; r < 4; ++r) {
                        int oy = mt * 16 + quad * 4 + r;
                        if (oy < 19)
                            h1[oy * ROW1 + ox * 12 + o] =
                                f2bf(fmaxf(acc1[q][mt][r] + bias, 0.f));
                    }
                }
            }
        }
    }
    __syncthreads();

    // ---- phase 3: conv2 MFMA  M=112(100), N=32(20), K=1280(1000) ----
    // Tiles: wave0 -> {0,1,2,3}, wave1 -> {4,5,6,dummy}. 40 unrolled steps,
    // distance-1 weight prefetch in named SSA vars.
    int abase[4];
#pragma unroll
    for (int mt = 0; mt < 4; ++mt) {
        int m = (wave * 4 + mt) * 16 + lm;
        if (m > 99) m = 99;                  // dummy/pad rows: duplicate
        int y = m / 10, xx = m - 10 * y;
        abase[mt] = y * ROW1 + xx * 12 + quad * 8;
    }
    f32x4 acc[4][2] = {};
    {
        const unsigned short* wptr = wbuf2 + lane * 8;
        s16x8 wc0 = *(const s16x8*)(wptr);
        s16x8 wc1 = *(const s16x8*)(wptr + 512);
#pragma unroll
        for (int it = 0; it < 40; ++it) {
            s16x8 wn0 = *(const s16x8*)(wptr + (it + 1) * 1024);   // tail -> conv3 region
            s16x8 wn1 = *(const s16x8*)(wptr + (it + 1) * 1024 + 512);
            const unsigned short* sbi = h1 + (it >> 2) * ROW1 + (it & 3) * 32;
            s16x8 af[4];
#pragma unroll
            for (int mt = 0; mt < 4; ++mt) {
                const unsigned short* p = sbi + abase[mt];
                af[mt] = cat8(*(const s16x4*)(p), *(const s16x4*)(p + 4));
            }
#pragma unroll
            for (int mt = 0; mt < 4; ++mt) {
                acc[mt][0] = __builtin_amdgcn_mfma_f32_16x16x32_bf16(af[mt], wc0, acc[mt][0], 0, 0, 0);
                acc[mt][1] = __builtin_amdgcn_mfma_f32_16x16x32_bf16(af[mt], wc1, acc[mt][1], 0, 0, 0);
            }
            wc0 = wn0; wc1 = wn1;
        }
    }
    __syncthreads();   // h1 fully consumed by both waves; region becomes h2s

    // ---- phase 4: zero h2 row-pads + scatter conv2 -> h2s ([x*20+c]) ----
    for (int e = tid; e < 120; e += 128) {             // pads [200,248) x 10
        int row = e / 12, seg = e - row * 12;
        *(s16x4*)(h2s + row * ROW2 + 200 + seg * 4) = (s16x4){0, 0, 0, 0};
    }
#pragma unroll
    for (int mt = 0; mt < 4; ++mt) {
        int mtg = wave * 4 + mt;
        if (mtg < 7) {                                  // skip wave1 dummy
#pragma unroll
            for (int nt = 0; nt < 2; ++nt) {
                int o = nt * 16 + lm;
                if (o < 20) {
                    float bias = b2[o];
#pragma unroll
                    for (int r = 0; r < 4; ++r) {
                        int pos = mtg * 16 + quad * 4 + r;
                        if (pos < 100) {
                            int y2 = pos / 10, x2 = pos - 10 * y2;
                            h2s[y2 * ROW2 + x2 * 20 + o] =
                                f2bf(fmaxf(acc[mt][nt][r] + bias, 0.f));
                        }
                    }
                }
            }
        }
    }
    __syncthreads();

    // ---- phase 5: conv3 MFMA  M=48(36), N=32(20), K=640(500) ----
    // Tiles: wave0 -> {0,1}, wave1 -> {2,dummy}. 20 unrolled steps.
    int abase3[2];
#pragma unroll
    for (int mt = 0; mt < 2; ++mt) {
        int m = (wave * 2 + mt) * 16 + lm;
        if (m > 35) m = 35;
        int oy = m / 6, ox = m - 6 * oy;
        abase3[mt] = oy * ROW2 + ox * 20 + quad * 8;
    }
    f32x4 acc3[2][2] = {};
    {
        const unsigned short* wptr = wbuf3 + lane * 8;
        s16x8 wc0 = *(const s16x8*)(wptr);
        s16x8 wc1 = *(const s16x8*)(wptr + 512);
#pragma unroll
        for (int it = 0; it < 20; ++it) {
            s16x8 wn0 = *(const s16x8*)(wptr + (it + 1) * 1024);   // tail -> wband
            s16x8 wn1 = *(const s16x8*)(wptr + (it + 1) * 1024 + 512);
            const unsigned short* sbi = h2s + (it >> 2) * ROW2 + (it & 3) * 32;
            s16x8 af[2];
#pragma unroll
            for (int mt = 0; mt < 2; ++mt) {
                const unsigned short* p = sbi + abase3[mt];
                af[mt] = cat8(*(const s16x4*)(p), *(const s16x4*)(p + 4));
            }
#pragma unroll
            for (int mt = 0; mt < 2; ++mt) {
                acc3[mt][0] = __builtin_amdgcn_mfma_f32_16x16x32_bf16(af[mt], wc0, acc3[mt][0], 0, 0, 0);
                acc3[mt][1] = __builtin_amdgcn_mfma_f32_16x16x32_bf16(af[mt], wc1, acc3[mt][1], 0, 0, 0);
            }
            wc0 = wn0; wc1 = wn1;
        }
    }
    __syncthreads();   // h2s consumed by both waves; region becomes h3s

    // ---- phase 6: conv3 epilogue -> linear h3s[o*36+pos] (fp32, relu) ----
#pragma unroll
    for (int mt = 0; mt < 2; ++mt) {
        int mtg = wave * 2 + mt;
        if (mtg < 3) {                                  // skip wave1 dummy
#pragma unroll
            for (int nt = 0; nt < 2; ++nt) {
                int o = nt * 16 + lm;
                if (o < 20) {
                    float b3v = b3[o];
#pragma unroll
                    for (int r = 0; r < 4; ++r) {
                        int pos = mtg * 16 + quad * 4 + r;
                        if (pos < 36)
                            h3s[o * 36 + pos] = fmaxf(acc3[mt][nt][r] + b3v, 0.f);
                    }
                }
            }
        }
    }
    __syncthreads();

    // ---- phase 7: fc — coalesced global wf; 128 threads; 2-wave reduce ----
    float part[10];
#pragma unroll
    for (int n = 0; n < 10; ++n) part[n] = 0.f;
#pragma unroll 1
    for (int s = 0; s < 6; ++s) {
        int k = s * 128 + tid;
        if (k < 720) {
            float v = h3s[k];
#pragma unroll
            for (int n = 0; n < 10; ++n)
                part[n] = fmaf(v, wf[n * 720 + k], part[n]);
        }
    }
#pragma unroll
    for (int n = 0; n < 10; ++n) {
#pragma unroll
        for (int off = 32; off >= 1; off >>= 1)
            part[n] += __shfl_xor(part[n], off, 64);
    }
    if (lane == 0) {
#pragma unroll
        for (int n = 0; n < 10; ++n) fcp[wave * 10 + n] = part[n];
    }
    __syncthreads();
    if (tid < 10)
        out[(size_t)b * 10 + tid] = fcp[tid] + fcp[10 + tid] + bf[tid];
}

extern "C" void kernel_launch(void* const* d_in, const int* in_sizes, int n_in,
                              void* d_out, int out_size, void* d_ws, size_t ws_size,
                              hipStream_t stream) {
    (void)n_in; (void)out_size; (void)ws_size;
    const float* x  = (const float*)d_in[0];
    const float* w1 = (const float*)d_in[1];
    const float* b1 = (const float*)d_in[2];
    const float* w2 = (const float*)d_in[3];
    const float* b2 = (const float*)d_in[4];
    const float* w3 = (const float*)d_in[5];
    const float* b3 = (const float*)d_in[6];
    const float* wf = (const float*)d_in[7];
    const float* bf = (const float*)d_in[8];
    float* out = (float*)d_out;

    const int B = in_sizes[0] / 784;                   // 4096

    unsigned short* wbuf = (unsigned short*)d_ws;      // 116736 bf16 = 228 KB

    wprep_k<<<456, 256, 0, stream>>>(w1, w2, w3, wbuf);
    fused_k<<<B, 128, 0, stream>>>(x, b1, wbuf, wbuf + 40960, wbuf + 61440,
                                   b2, b3, wf, bf, out);
}

// Round 13
// 146.069 us; speedup vs baseline: 1.3008x; 1.0574x over previous
//
#include <hip/hip_runtime.h>

// LeNet-5 forward, fully fused, TWO WAVES PER IMAGE (128-thread blocks).
// ALL three convs on bf16 MFMA (16x16x32); only epilogues + fc on VALU.
//
// Round-13 (on round-12 base):
//  (1) distance-1 A-fragment prefetch in conv2/conv3 K-loops (named arrays,
//      constant indices under full unroll -> registers, no scratch): step it's
//      MFMAs consume fragments loaded in step it-1, hiding ~120cyc LDS latency
//      per wave instead of stalling on lgkmcnt every step.
//  (2) no dummy tiles: conv2 wave0={0,1,2,3} wave1={4,5,6}; conv3 wave0={0,1}
//      wave1={2}; 4th/2nd tile guarded by wave-uniform branches (-12% MFMA,
//      -11% LDS vs round 12).
// __launch_bounds__(128,4): 128-reg unified cap, working set ~112, no spill.
//
// Layouts (unchanged from round 7):
//   conv1 as GEMM (row-only im2col), banded weights K=288, N=192.
//   h1: bf16 19x248 ([x*12+c], pads zeroed)  -- stride 248 = conflict-free
//   h2: bf16 10x248 ([x*20+c], pads zeroed)
//   all K-padding baked into pre-packed weights (zeros).

typedef short s16x4 __attribute__((ext_vector_type(4)));
typedef short s16x8 __attribute__((ext_vector_type(8)));
typedef float f32x4 __attribute__((ext_vector_type(4)));

#define ROW1 248
#define ROW2 248
#define XOFF 4712           // xbf elem offset (= 19*248)
#define SM_BYTES 11024

static __device__ __forceinline__ unsigned short f2bf(float f) {
    union { float f; unsigned int u; } v; v.f = f;
    unsigned int u = v.u;
    unsigned int r = (u + 0x7fffu + ((u >> 16) & 1u)) >> 16;   // RNE
    return (unsigned short)r;
}

static __device__ __forceinline__ s16x8 cat8(s16x4 lo, s16x4 hi) {
    return __builtin_shufflevector(lo, hi, 0, 1, 2, 3, 4, 5, 6, 7);
}

// ---- weight prep ----------------------------------------------------------
// wbuf ushort: [0,40960) conv2 B-frags, [40960,61440) conv3 B-frags,
//              [61440,116736) conv1 banded B-frags (wband).
// All use the 16x16x32 B-frag convention: n = nt*16 + (lane&15),
// k = kc*32 + ((lane>>4)&3)*8 + t.
__global__ __launch_bounds__(256) void wprep_k(const float* __restrict__ w1,
                                               const float* __restrict__ w2,
                                               const float* __restrict__ w3,
                                               unsigned short* __restrict__ wbuf) {
    int e = blockIdx.x * 256 + threadIdx.x;
    if (e < 40960) {                       // conv2: j=k/12, c=k%12
        int t = e & 7, lane = (e >> 3) & 63, nt = (e >> 9) & 1;
        int ck = (e >> 10) & 3, i = e >> 12;
        int k = ck * 32 + ((lane >> 4) & 3) * 8 + t;
        int o = nt * 16 + (lane & 15);
        int j = k / 12, c = k % 12;
        float val = (j < 10 && c < 10 && o < 20) ? w2[o * 1000 + c * 100 + i * 10 + j] : 0.f;
        wbuf[e] = f2bf(val);
    } else if (e < 61440) {                // conv3: j=k/20, c=k%20
        int e2 = e - 40960;
        int t = e2 & 7, lane = (e2 >> 3) & 63, nt = (e2 >> 9) & 1;
        int ck = (e2 >> 10) & 3, i = e2 >> 12;
        int k = ck * 32 + ((lane >> 4) & 3) * 8 + t;
        int o = nt * 16 + (lane & 15);
        int j = k / 20, c = k % 20;
        float val = (j < 5 && o < 20) ? w3[o * 500 + c * 25 + i * 5 + j] : 0.f;
        wbuf[e] = f2bf(val);
    } else {                               // conv1 band: [nt(12)][kc(9)][lane][t]
        int e2 = e - 61440;                // < 55296
        int t = e2 & 7, lane = (e2 >> 3) & 63;
        int kc = (e2 >> 9) % 9, nt = (e2 >> 9) / 9;
        int n = nt * 16 + (lane & 15);
        int k = kc * 32 + ((lane >> 4) & 3) * 8 + t;
        float val = 0.f;
        if (n < 190 && k < 280) {
            int ox = n / 10, o = n - ox * 10;
            int i = k / 28, xc = k - i * 28;
            int j = xc - ox;
            if (j >= 0 && j < 10) val = w1[o * 100 + i * 10 + j];
        }
        wbuf[61440 + e2] = f2bf(val);
    }
}

// --------------------------- the fused kernel ------------------------------
__global__ __launch_bounds__(128, 4) void fused_k(const float* __restrict__ x,
                                                  const float* __restrict__ b1,
                                                  const unsigned short* __restrict__ wbuf2,
                                                  const unsigned short* __restrict__ wbuf3,
                                                  const unsigned short* __restrict__ wband,
                                                  const float* __restrict__ b2,
                                                  const float* __restrict__ b3,
                                                  const float* __restrict__ wf,
                                                  const float* __restrict__ bf,
                                                  float* __restrict__ out) {
    __shared__ __align__(16) unsigned char smem[SM_BYTES];
    unsigned short* sm16 = (unsigned short*)smem;
    unsigned short* h1  = sm16;                 // [0, 4712) elems
    unsigned short* xbf = sm16 + XOFF;          // [4712, 5512) elems
    unsigned short* h2s = sm16;                 // later: [0, 2480) elems
    float*          h3s = (float*)smem;         // later: [0, 720) floats
    float*          fcp = (float*)(smem + 2880);// fc partials (20 floats)

    const int tid = threadIdx.x;
    const int wave = tid >> 6, lane = tid & 63;
    const int b = blockIdx.x;
    const int quad = lane >> 4, lm = lane & 15;

    // ---- phase 1: stage x as bf16; zero xbf tail, h1 row-pads & c-pads ----
    {
        const float4* src = (const float4*)(x + (size_t)b * 784);
        for (int k = tid; k < 196; k += 128) {
            float4 v = src[k];
            s16x4 p = { (short)f2bf(v.x), (short)f2bf(v.y),
                        (short)f2bf(v.z), (short)f2bf(v.w) };
            *(s16x4*)(xbf + k * 4) = p;
        }
        if (tid < 16) xbf[784 + tid] = 0;
        for (int e = tid; e < 95; e += 128) {          // row pads [228,248) x 19
            int row = e / 5, seg = e - row * 5;
            *(s16x4*)(h1 + row * ROW1 + 228 + seg * 4) = (s16x4){0, 0, 0, 0};
        }
        for (int e = tid; e < 361; e += 128) {         // c-pads (oy,ox,[10,12))
            int oy = e / 19, ox = e - oy * 19;
            *(unsigned int*)(h1 + oy * ROW1 + ox * 12 + 10) = 0u;
        }
    }
    __syncthreads();

    // ---- phase 2: conv1 MFMA  M=32(19), N=192(190), K=288(280) ----
    // nt-group g == wave (6 nt each): exact 2-way split.
    {
        int m1 = lm + 16; if (m1 > 18) m1 = 18;        // clamp pad rows
        const unsigned short* ab0 = xbf + lm * 28 + quad * 8;
        const unsigned short* ab1 = xbf + m1 * 28 + quad * 8;
        const unsigned short* wb = wband + lane * 8;
        f32x4 acc1[6][2] = {};
#pragma unroll
        for (int kc = 0; kc < 9; ++kc) {
            s16x8 a0 = cat8(*(const s16x4*)(ab0 + kc * 32),
                            *(const s16x4*)(ab0 + kc * 32 + 4));
            s16x8 a1 = cat8(*(const s16x4*)(ab1 + kc * 32),
                            *(const s16x4*)(ab1 + kc * 32 + 4));
#pragma unroll
            for (int q = 0; q < 6; ++q) {
                int nt = wave * 6 + q;
                s16x8 bw = *(const s16x8*)(wb + (nt * 9 + kc) * 512);
                acc1[q][0] = __builtin_amdgcn_mfma_f32_16x16x32_bf16(a0, bw, acc1[q][0], 0, 0, 0);
                acc1[q][1] = __builtin_amdgcn_mfma_f32_16x16x32_bf16(a1, bw, acc1[q][1], 0, 0, 0);
            }
        }
#pragma unroll
        for (int q = 0; q < 6; ++q) {
            int n = (wave * 6 + q) * 16 + lm;
            if (n < 190) {
                int ox = n / 10, o = n - ox * 10;
                float bias = b1[o];
#pragma unroll
                for (int mt = 0; mt < 2; ++mt) {
#pragma unroll
                    for (int r = 0; r < 4; ++r) {
                        int oy = mt * 16 + quad * 4 + r;
                        if (oy < 19)
                            h1[oy * ROW1 + ox * 12 + o] =
                                f2bf(fmaxf(acc1[q][mt][r] + bias, 0.f));
                    }
                }
            }
        }
    }
    __syncthreads();

    // ---- phase 3: conv2 MFMA  M=112(100), N=32(20), K=1280(1000) ----
    // Tiles: wave0 -> {0,1,2,3}, wave1 -> {4,5,6}. 40 unrolled steps;
    // distance-1 prefetch of BOTH weights (global) and A-frags (LDS).
    int abase[4];
#pragma unroll
    for (int mt = 0; mt < 4; ++mt) {
        int tg = (wave == 0) ? mt : 4 + mt;            // wave1 mt=3 unused
        int m = tg * 16 + lm;
        if (m > 99) m = 99;
        int y = m / 10, xx = m - 10 * y;
        abase[mt] = y * ROW1 + xx * 12 + quad * 8;
    }
    f32x4 acc[4][2] = {};
    {
        const unsigned short* wptr = wbuf2 + lane * 8;
        s16x8 wc0 = *(const s16x8*)(wptr);
        s16x8 wc1 = *(const s16x8*)(wptr + 512);
        s16x8 afc[4], afn[4];
        {
            const unsigned short* sbi = h1;            // it=0
#pragma unroll
            for (int mt = 0; mt < 3; ++mt)
                afc[mt] = cat8(*(const s16x4*)(sbi + abase[mt]),
                               *(const s16x4*)(sbi + abase[mt] + 4));
            if (wave == 0)
                afc[3] = cat8(*(const s16x4*)(sbi + abase[3]),
                              *(const s16x4*)(sbi + abase[3] + 4));
            else
                afc[3] = afc[2];
        }
#pragma unroll
        for (int it = 0; it < 40; ++it) {
            s16x8 wn0 = *(const s16x8*)(wptr + (it + 1) * 1024);   // tail->conv3 region
            s16x8 wn1 = *(const s16x8*)(wptr + (it + 1) * 1024 + 512);
            const unsigned short* sbn = h1 + ((it + 1) >> 2) * ROW1 + ((it + 1) & 3) * 32;
#pragma unroll
            for (int mt = 0; mt < 3; ++mt)
                afn[mt] = cat8(*(const s16x4*)(sbn + abase[mt]),
                               *(const s16x4*)(sbn + abase[mt] + 4));
            if (wave == 0)
                afn[3] = cat8(*(const s16x4*)(sbn + abase[3]),
                              *(const s16x4*)(sbn + abase[3] + 4));
            else
                afn[3] = afc[3];
#pragma unroll
            for (int mt = 0; mt < 3; ++mt) {
                acc[mt][0] = __builtin_amdgcn_mfma_f32_16x16x32_bf16(afc[mt], wc0, acc[mt][0], 0, 0, 0);
                acc[mt][1] = __builtin_amdgcn_mfma_f32_16x16x32_bf16(afc[mt], wc1, acc[mt][1], 0, 0, 0);
            }
            if (wave == 0) {
                acc[3][0] = __builtin_amdgcn_mfma_f32_16x16x32_bf16(afc[3], wc0, acc[3][0], 0, 0, 0);
                acc[3][1] = __builtin_amdgcn_mfma_f32_16x16x32_bf16(afc[3], wc1, acc[3][1], 0, 0, 0);
            }
            wc0 = wn0; wc1 = wn1;
#pragma unroll
            for (int mt = 0; mt < 4; ++mt) afc[mt] = afn[mt];
        }
    }
    __syncthreads();   // h1 fully consumed by both waves; region becomes h2s

    // ---- phase 4: zero h2 row-pads + scatter conv2 -> h2s ([x*20+c]) ----
    for (int e = tid; e < 120; e += 128) {             // pads [200,248) x 10
        int row = e / 12, seg = e - row * 12;
        *(s16x4*)(h2s + row * ROW2 + 200 + seg * 4) = (s16x4){0, 0, 0, 0};
    }
#pragma unroll
    for (int mt = 0; mt < 4; ++mt) {
        int tg = (wave == 0) ? mt : 4 + mt;
        if (wave == 0 || mt < 3) {
#pragma unroll
            for (int nt = 0; nt < 2; ++nt) {
                int o = nt * 16 + lm;
                if (o < 20) {
                    float bias = b2[o];
#pragma unroll
                    for (int r = 0; r < 4; ++r) {
                        int pos = tg * 16 + quad * 4 + r;
                        if (pos < 100) {
                            int y2 = pos / 10, x2 = pos - 10 * y2;
                            h2s[y2 * ROW2 + x2 * 20 + o] =
                                f2bf(fmaxf(acc[mt][nt][r] + bias, 0.f));
                        }
                    }
                }
            }
        }
    }
    __syncthreads();

    // ---- phase 5: conv3 MFMA  M=48(36), N=32(20), K=640(500) ----
    // Tiles: wave0 -> {0,1}, wave1 -> {2}. 20 unrolled steps; dual prefetch.
    int abase3[2];
    {
        int tg0 = (wave == 0) ? 0 : 2;
        int m0 = tg0 * 16 + lm; if (m0 > 35) m0 = 35;
        int oy0 = m0 / 6, ox0 = m0 - 6 * oy0;
        abase3[0] = oy0 * ROW2 + ox0 * 20 + quad * 8;
        int m1 = 16 + lm; if (m1 > 35) m1 = 35;        // tile 1 (wave0 only)
        int oy1 = m1 / 6, ox1 = m1 - 6 * oy1;
        abase3[1] = oy1 * ROW2 + ox1 * 20 + quad * 8;
    }
    f32x4 acc3[2][2] = {};
    {
        const unsigned short* wptr = wbuf3 + lane * 8;
        s16x8 wc0 = *(const s16x8*)(wptr);
        s16x8 wc1 = *(const s16x8*)(wptr + 512);
        s16x8 afc[2], afn[2];
        {
            const unsigned short* sbi = h2s;           // it=0
            afc[0] = cat8(*(const s16x4*)(sbi + abase3[0]),
                          *(const s16x4*)(sbi + abase3[0] + 4));
            if (wave == 0)
                afc[1] = cat8(*(const s16x4*)(sbi + abase3[1]),
                              *(const s16x4*)(sbi + abase3[1] + 4));
            else
                afc[1] = afc[0];
        }
#pragma unroll
        for (int it = 0; it < 20; ++it) {
            s16x8 wn0 = *(const s16x8*)(wptr + (it + 1) * 1024);   // tail -> wband
            s16x8 wn1 = *(const s16x8*)(wptr + (it + 1) * 1024 + 512);
            const unsigned short* sbn = h2s + ((it + 1) >> 2) * ROW2 + ((it + 1) & 3) * 32;
            afn[0] = cat8(*(const s16x4*)(sbn + abase3[0]),
                          *(const s16x4*)(sbn + abase3[0] + 4));
            if (wave == 0)
                afn[1] = cat8(*(const s16x4*)(sbn + abase3[1]),
                              *(const s16x4*)(sbn + abase3[1] + 4));
            else
                afn[1] = afc[1];
            acc3[0][0] = __builtin_amdgcn_mfma_f32_16x16x32_bf16(afc[0], wc0, acc3[0][0], 0, 0, 0);
            acc3[0][1] = __builtin_amdgcn_mfma_f32_16x16x32_bf16(afc[0], wc1, acc3[0][1], 0, 0, 0);
            if (wave == 0) {
                acc3[1][0] = __builtin_amdgcn_mfma_f32_16x16x32_bf16(afc[1], wc0, acc3[1][0], 0, 0, 0);
                acc3[1][1] = __builtin_amdgcn_mfma_f32_16x16x32_bf16(afc[1], wc1, acc3[1][1], 0, 0, 0);
            }
            wc0 = wn0; wc1 = wn1;
            afc[0] = afn[0]; afc[1] = afn[1];
        }
    }
    __syncthreads();   // h2s consumed by both waves; region becomes h3s

    // ---- phase 6: conv3 epilogue -> linear h3s[o*36+pos] (fp32, relu) ----
#pragma unroll
    for (int mt = 0; mt < 2; ++mt) {
        int tg = (mt == 0) ? ((wave == 0) ? 0 : 2) : 1;
        if (wave == 0 || mt < 1) {
#pragma unroll
            for (int nt = 0; nt < 2; ++nt) {
                int o = nt * 16 + lm;
                if (o < 20) {
                    float b3v = b3[o];
#pragma unroll
                    for (int r = 0; r < 4; ++r) {
                        int pos = tg * 16 + quad * 4 + r;
                        if (pos < 36)
                            h3s[o * 36 + pos] = fmaxf(acc3[mt][nt][r] + b3v, 0.f);
                    }
                }
            }
        }
    }
    __syncthreads();

    // ---- phase 7: fc — coalesced global wf; 128 threads; 2-wave reduce ----
    float part[10];
#pragma unroll
    for (int n = 0; n < 10; ++n) part[n] = 0.f;
#pragma unroll 1
    for (int s = 0; s < 6; ++s) {
        int k = s * 128 + tid;
        if (k < 720) {
            float v = h3s[k];
#pragma unroll
            for (int n = 0; n < 10; ++n)
                part[n] = fmaf(v, wf[n * 720 + k], part[n]);
        }
    }
#pragma unroll
    for (int n = 0; n < 10; ++n) {
#pragma unroll
        for (int off = 32; off >= 1; off >>= 1)
            part[n] += __shfl_xor(part[n], off, 64);
    }
    if (lane == 0) {
#pragma unroll
        for (int n = 0; n < 10; ++n) fcp[wave * 10 + n] = part[n];
    }
    __syncthreads();
    if (tid < 10)
        out[(size_t)b * 10 + tid] = fcp[tid] + fcp[10 + tid] + bf[tid];
}

extern "C" void kernel_launch(void* const* d_in, const int* in_sizes, int n_in,
                              void* d_out, int out_size, void* d_ws, size_t ws_size,
                              hipStream_t stream) {
    (void)n_in; (void)out_size; (void)ws_size;
    const float* x  = (const float*)d_in[0];
    const float* w1 = (const float*)d_in[1];
    const float* b1 = (const float*)d_in[2];
    const float* w2 = (const float*)d_in[3];
    const float* b2 = (const float*)d_in[4];
    const float* w3 = (const float*)d_in[5];
    const float* b3 = (const float*)d_in[6];
    const float* wf = (const float*)d_in[7];
    const float* bf = (const float*)d_in[8];
    float* out = (float*)d_out;

    const int B = in_sizes[0] / 784;                   // 4096

    unsigned short* wbuf = (unsigned short*)d_ws;      // 116736 bf16 = 228 KB

    wprep_k<<<456, 256, 0, stream>>>(w1, w2, w3, wbuf);
    fused_k<<<B, 128, 0, stream>>>(x, b1, wbuf, wbuf + 40960, wbuf + 61440,
                                   b2, b3, wf, bf, out);
}